// Round 4
// baseline (937.377 us; speedup 1.0000x reference)
//
#include <hip/hip_runtime.h>

#define NTOK 64
#define DIM 192
#define HD 32
#define W 8            // windows per block (pipelined)

// LDS strides (bf16 elems unless noted):
//   RS=200 (100 dw == 4 mod 32): b128 reads 8 dw/bank; b64 writes 4 dw/bank.
//   VTS=68 (34 dw == 2 mod 32): b128 reads 8 dw/bank; b64 writes 4 dw/bank.
//   MS=68 (float stride): mask rows; float4 writes 8 dw/bank, b32 reads 2-way (free).
// LDS = ksm 25600 + vsT 26112 + osm 25600 + mlds 17408 = 94720 B -> 1 block/CU.
// (Occupancy proven irrelevant 23% vs 33% in r0-r3; this round bets on
//  intra-wave cross-window ILP instead of TLP.)
#define RS  200
#define VTS 68
#define MS  68
#define WQN (576 * DIM)
#define WPN (DIM * DIM)

typedef __attribute__((ext_vector_type(8))) short short8;
typedef __attribute__((ext_vector_type(4))) float floatx4;
typedef __attribute__((ext_vector_type(2))) unsigned int uint2v;

__device__ __forceinline__ short f2bf(float f) {
    union { float f; unsigned int u; } c; c.f = f;
    unsigned int r = (c.u + 0x7FFFu + ((c.u >> 16) & 1u)) >> 16;
    return (short)(unsigned short)r;
}

// pack two fp32 -> two bf16 (RNE) in one dword: low16=bf(a), high16=bf(b)
__device__ __forceinline__ unsigned pkbf(float a, float b) {
    unsigned ua = __float_as_uint(a); ua += 0x7FFFu + ((ua >> 16) & 1u);
    unsigned ub = __float_as_uint(b); ub += 0x7FFFu + ((ub >> 16) & 1u);
    return __builtin_amdgcn_perm(ub, ua, 0x07060302u);
}

// 8 consecutive fp32 (16B-aligned) -> bf16x8 fragment (ascending k order)
__device__ __forceinline__ short8 cvt8(const float* p) {
    const float4* v = reinterpret_cast<const float4*>(p);
    float4 lo = v[0], hi = v[1];
    union { unsigned u[4]; short8 s; } r;
    r.u[0] = pkbf(lo.x, lo.y);
    r.u[1] = pkbf(lo.z, lo.w);
    r.u[2] = pkbf(hi.x, hi.y);
    r.u[3] = pkbf(hi.z, hi.w);
    return r.s;
}

// Quad-exchange: two MFMA-D-layout fp32 tiles (v0: rows 0..15, v1: rows 16..31;
// row = 16t + 4*quad + g, col = lane&15) -> bf16 A/B-fragment for K=32:
// lane (r,q) receives rows 8q+j (j=0..7), col r.
__device__ __forceinline__ short8 qshuf(floatx4 v0, floatx4 v1, int lane) {
    const int q = lane >> 4;
    const unsigned p0a = pkbf(v0[0], v0[1]);   // t=0, g={0,1}
    const unsigned p0b = pkbf(v0[2], v0[3]);   // t=0, g={2,3}
    const unsigned p1a = pkbf(v1[0], v1[1]);   // t=1, g={0,1}
    const unsigned p1b = pkbf(v1[2], v1[3]);   // t=1, g={2,3}
    const int s0 = (lane & 15) | ((q & 1) << 5);   // src quad 2(q&1)   (d=0,1)
    const int s1 = s0 + 16;                        // src quad 2(q&1)+1 (d=2,3)
    const unsigned l0 = (unsigned)__shfl((int)p0a, s0);
    const unsigned h0 = (unsigned)__shfl((int)p1a, s0);
    const unsigned l1 = (unsigned)__shfl((int)p0b, s0);
    const unsigned h1 = (unsigned)__shfl((int)p1b, s0);
    const unsigned l2 = (unsigned)__shfl((int)p0a, s1);
    const unsigned h2 = (unsigned)__shfl((int)p1a, s1);
    const unsigned l3 = (unsigned)__shfl((int)p0b, s1);
    const unsigned h3 = (unsigned)__shfl((int)p1b, s1);
    const bool hi = q >= 2;                        // tile select t = q>>1
    union { unsigned u[4]; short8 s; } ret;
    ret.u[0] = hi ? h0 : l0;
    ret.u[1] = hi ? h1 : l1;
    ret.u[2] = hi ? h2 : l2;
    ret.u[3] = hi ? h3 : l3;
    return ret.s;
}

// One-time (per launch) fp32 -> bf16 weight conversion into workspace.
// Q rows (0..191) of wqkv get the 1/sqrt(32) scale folded in.
__global__ void wprep(const float* __restrict__ wqkv, const float* __restrict__ wproj,
                      short* __restrict__ wqb, short* __restrict__ wpb) {
    const int i = blockIdx.x * 256 + (int)threadIdx.x;
    for (int e = i; e < WQN; e += 192 * 256) {
        float v = wqkv[e];
        if (e < DIM * DIM) v *= 0.17677669529663688f;
        wqb[e] = f2bf(v);
    }
    for (int e = i; e < WPN; e += 192 * 256) wpb[e] = f2bf(wproj[e]);
}

template <int WS>
__global__ __launch_bounds__(256, 1)
void wattn_fused(const float* __restrict__ x, const float* __restrict__ mask,
                 const float* __restrict__ wqkv, const float* __restrict__ wproj,
                 const float* __restrict__ bproj, float* __restrict__ out,
                 const short* __restrict__ wqb, const short* __restrict__ wpb) {
    __shared__ short ksm[NTOK * RS];   // K  [token][kdim]
    __shared__ short vsT[DIM * VTS];   // V^T[vdim][token]
    __shared__ short osm[NTOK * RS];   // O  [token][outdim]
    __shared__ float mlds[NTOK * MS];  // mask [key][query], padded stride

    const int bw0  = (int)blockIdx.x * W;
    const int tid  = (int)threadIdx.x;
    const int wave = tid >> 6;
    const int lane = tid & 63;
    const int r    = lane & 15;
    const int q    = lane >> 4;

    auto ldq = [&](int off) -> short8 {      // wqkv fragment (bf16 ws or fp32+cvt)
        if constexpr (WS) return *reinterpret_cast<const short8*>(wqb + off);
        else              return cvt8(wqkv + off);
    };
    auto ldp = [&](int off) -> short8 {      // wproj fragment
        if constexpr (WS) return *reinterpret_cast<const short8*>(wpb + off);
        else              return cvt8(wproj + off);
    };

    // Cross-window X prefetch registers (fp32, 192 VGPR; budget is 512 at
    // launch_bounds(256,1) so no spill — r1's spill was a 168-budget artifact).
    float4 xp[4][6][2];
    auto xload = [&](const float* xb) {
        #pragma unroll
        for (int mt = 0; mt < 4; ++mt) {
            #pragma unroll
            for (int s = 0; s < 6; ++s) {
                const float4* v = reinterpret_cast<const float4*>(
                    xb + (mt * 16 + r) * DIM + s * 32 + q * 8);
                xp[mt][s][0] = v[0];
                xp[mt][s][1] = v[1];
            }
        }
    };
    xload(x + (size_t)bw0 * (NTOK * DIM));   // prologue: window 0 (latency exposed once)

    #pragma unroll 1
    for (int w = 0; w < W; ++w) {
        const int bw = bw0 + w;

        // ---- consume prefetched X -> bf16 fragments (lane r=token, k=s*32+q*8+j)
        short8 a[4][6];
        #pragma unroll
        for (int mt = 0; mt < 4; ++mt) {
            #pragma unroll
            for (int s = 0; s < 6; ++s) {
                union { unsigned u[4]; short8 s8; } t;
                t.u[0] = pkbf(xp[mt][s][0].x, xp[mt][s][0].y);
                t.u[1] = pkbf(xp[mt][s][0].z, xp[mt][s][0].w);
                t.u[2] = pkbf(xp[mt][s][1].x, xp[mt][s][1].y);
                t.u[3] = pkbf(xp[mt][s][1].z, xp[mt][s][1].w);
                a[mt][s] = t.s8;
            }
        }

        // ---- mask for CURRENT window: issue loads now, ds_write before barrier (T14)
        const float* mbW = mask + (size_t)bw * (NTOK * NTOK);
        float4 mreg[4];
        #pragma unroll
        for (int it = 0; it < 4; ++it)
            mreg[it] = *reinterpret_cast<const float4*>(mbW + it * 1024 + tid * 4);

        // ---- prefetch NEXT window's X (lands during P1+P2+P3 of this window)
        if (w + 1 < W) xload(x + (size_t)(bw + 1) * (NTOK * DIM));

        // ---------------- Phase 1: K (waves 0,1) / V (waves 2,3) -> LDS ----------------
        if (wave < 2) {
            #pragma unroll 1
            for (int nt = 0; nt < 6; ++nt) {
                const int dk = wave * 96 + nt * 16;
                floatx4 acc[4];
                #pragma unroll
                for (int mt = 0; mt < 4; ++mt) acc[mt] = (floatx4){0.f, 0.f, 0.f, 0.f};
                #pragma unroll
                for (int s = 0; s < 6; ++s) {
                    const short8 b8 = ldq((DIM + dk + r) * DIM + s * 32 + q * 8);
                    #pragma unroll
                    for (int mt = 0; mt < 4; ++mt)  // swapped: D col=token, row=kdim
                        acc[mt] = __builtin_amdgcn_mfma_f32_16x16x32_bf16(b8, a[mt][s], acc[mt], 0, 0, 0);
                }
                #pragma unroll
                for (int mt = 0; mt < 4; ++mt) {    // 4 consecutive kdims -> one b64 store
                    uint2v u;
                    u.x = pkbf(acc[mt][0], acc[mt][1]);
                    u.y = pkbf(acc[mt][2], acc[mt][3]);
                    *reinterpret_cast<uint2v*>(ksm + (mt * 16 + r) * RS + dk + q * 4) = u;
                }
            }
        } else {
            #pragma unroll 1
            for (int nt = 0; nt < 6; ++nt) {
                const int dv = (wave - 2) * 96 + nt * 16;
                floatx4 acc[4];
                #pragma unroll
                for (int mt = 0; mt < 4; ++mt) acc[mt] = (floatx4){0.f, 0.f, 0.f, 0.f};
                #pragma unroll
                for (int s = 0; s < 6; ++s) {
                    const short8 b8 = ldq((2 * DIM + dv + r) * DIM + s * 32 + q * 8);
                    #pragma unroll
                    for (int mt = 0; mt < 4; ++mt)  // normal: D col=vdim, row=token
                        acc[mt] = __builtin_amdgcn_mfma_f32_16x16x32_bf16(a[mt][s], b8, acc[mt], 0, 0, 0);
                }
                #pragma unroll
                for (int mt = 0; mt < 4; ++mt) {    // 4 consecutive tokens -> one b64 store
                    uint2v u;
                    u.x = pkbf(acc[mt][0], acc[mt][1]);
                    u.y = pkbf(acc[mt][2], acc[mt][3]);
                    *reinterpret_cast<uint2v*>(vsT + (dv + r) * VTS + mt * 16 + q * 4) = u;
                }
            }
        }
        // mask -> LDS (each thread owns 4 rows x 4 cols; covered exactly once)
        #pragma unroll
        for (int it = 0; it < 4; ++it)
            *reinterpret_cast<float4*>(&mlds[(it * 16 + (tid >> 4)) * MS + (tid & 15) * 4]) = mreg[it];
        __syncthreads();   // K/V + mask staged

        // ------------- Phase 2: per unit = Q-compute + attention -> osm ------------
        #pragma unroll 1
        for (int i = 0; i < 3; ++i) {
            const int uu = wave * 3 + i, h = uu >> 1, half = uu & 1;

            // Q for this unit from live a[][] registers (no refetch)
            floatx4 qa[2][2];                       // [dim-subtile dt][query-tile qt]
            #pragma unroll
            for (int dt = 0; dt < 2; ++dt)
                #pragma unroll
                for (int qt = 0; qt < 2; ++qt) qa[dt][qt] = (floatx4){0.f, 0.f, 0.f, 0.f};
            #pragma unroll
            for (int s = 0; s < 6; ++s) {
                const short8 w0 = ldq((h * HD + r) * DIM + s * 32 + q * 8);
                const short8 w1 = ldq((h * HD + 16 + r) * DIM + s * 32 + q * 8);
                #pragma unroll
                for (int qt = 0; qt < 2; ++qt) {    // swapped: D col=token, row=qdim
                    qa[0][qt] = __builtin_amdgcn_mfma_f32_16x16x32_bf16(w0, a[half * 2 + qt][s], qa[0][qt], 0, 0, 0);
                    qa[1][qt] = __builtin_amdgcn_mfma_f32_16x16x32_bf16(w1, a[half * 2 + qt][s], qa[1][qt], 0, 0, 0);
                }
            }
            if constexpr (!WS) {                    // scale folded into weights when WS
                #pragma unroll
                for (int dt = 0; dt < 2; ++dt)
                    #pragma unroll
                    for (int qt = 0; qt < 2; ++qt)
                        #pragma unroll
                        for (int g = 0; g < 4; ++g)
                            qa[dt][qt][g] *= 0.17677669529663688f;
            }
            short8 bq0 = qshuf(qa[0][0], qa[1][0], lane);  // lane r=query, k=head dim
            short8 bq1 = qshuf(qa[0][1], qa[1][1], lane);

            short8 bk[4];
            #pragma unroll
            for (int kt = 0; kt < 4; ++kt)
                bk[kt] = *reinterpret_cast<const short8*>(ksm + (kt * 16 + r) * RS + h * HD + q * 8);

            // S^T = mfma(K, Q): lane col=query (r), row=key (kt*16 + q*4+g)
            floatx4 sa[4][2];
            #pragma unroll
            for (int kt = 0; kt < 4; ++kt) {
                floatx4 z = (floatx4){0.f, 0.f, 0.f, 0.f};
                sa[kt][0] = __builtin_amdgcn_mfma_f32_16x16x32_bf16(bk[kt], bq0, z, 0, 0, 0);
                sa[kt][1] = __builtin_amdgcn_mfma_f32_16x16x32_bf16(bk[kt], bq1, z, 0, 0, 0);
            }
            // additive mask from LDS (row=key=kt*16+4q+g, col=query)
            #pragma unroll
            for (int kt = 0; kt < 4; ++kt)
                #pragma unroll
                for (int qt = 0; qt < 2; ++qt)
                    #pragma unroll
                    for (int g = 0; g < 4; ++g)
                        sa[kt][qt][g] += mlds[(kt * 16 + 4 * q + g) * MS + half * 32 + qt * 16 + r];

            // softmax: 16 in-lane values + 2 cross-quad shuffles (keys live on quads)
            float rinv[2];
            #pragma unroll
            for (int qt = 0; qt < 2; ++qt) {
                float mx = sa[0][qt][0];
                #pragma unroll
                for (int kt = 0; kt < 4; ++kt)
                    #pragma unroll
                    for (int g = 0; g < 4; ++g) mx = fmaxf(mx, sa[kt][qt][g]);
                mx = fmaxf(mx, __shfl_xor(mx, 16));
                mx = fmaxf(mx, __shfl_xor(mx, 32));
                float sm = 0.f;
                #pragma unroll
                for (int kt = 0; kt < 4; ++kt) {
                    #pragma unroll
                    for (int g = 0; g < 4; ++g) {
                        float p = __expf(sa[kt][qt][g] - mx);
                        sa[kt][qt][g] = p;
                        sm += p;
                    }
                }
                sm += __shfl_xor(sm, 16);
                sm += __shfl_xor(sm, 32);
                rinv[qt] = 1.0f / sm;              // normalization deferred to O
            }

            // P fragments in-register
            short8 ap[2][2];
            #pragma unroll
            for (int qt = 0; qt < 2; ++qt) {
                #pragma unroll
                for (int kk = 0; kk < 2; ++kk)
                    ap[qt][kk] = qshuf(sa[2 * kk][qt], sa[2 * kk + 1][qt], lane);
            }

            short8 bv[2][2];
            #pragma unroll
            for (int nv = 0; nv < 2; ++nv)
                #pragma unroll
                for (int kk = 0; kk < 2; ++kk)
                    bv[nv][kk] = *reinterpret_cast<const short8*>(
                        vsT + (h * HD + nv * 16 + r) * VTS + kk * 32 + q * 8);

            // O^T = mfma(V^T, P^T): lane col=query (r) -> rinv lane-local; -> osm
            #pragma unroll
            for (int qt = 0; qt < 2; ++qt) {
                #pragma unroll
                for (int nv = 0; nv < 2; ++nv) {
                    floatx4 o = (floatx4){0.f, 0.f, 0.f, 0.f};
                    o = __builtin_amdgcn_mfma_f32_16x16x32_bf16(bv[nv][0], ap[qt][0], o, 0, 0, 0);
                    o = __builtin_amdgcn_mfma_f32_16x16x32_bf16(bv[nv][1], ap[qt][1], o, 0, 0, 0);
                    uint2v u;
                    u.x = pkbf(o[0] * rinv[qt], o[1] * rinv[qt]);
                    u.y = pkbf(o[2] * rinv[qt], o[3] * rinv[qt]);
                    *reinterpret_cast<uint2v*>(
                        osm + (half * 32 + qt * 16 + r) * RS + h * HD + nv * 16 + q * 4) = u;
                }
            }
        }
        __syncthreads();   // osm complete

        // ---------------- Phase 3: out = O * Wproj^T + b ----------------
        short8 ao[4][6];
        #pragma unroll
        for (int mt = 0; mt < 4; ++mt) {
            #pragma unroll
            for (int s = 0; s < 6; ++s)
                ao[mt][s] = *reinterpret_cast<const short8*>(osm + (mt * 16 + r) * RS + s * 32 + q * 8);
        }

        float* ob = out + (size_t)bw * (NTOK * DIM);
        #pragma unroll 1
        for (int nt = 0; nt < 3; ++nt) {
            const int d0 = wave * 48 + nt * 16;
            const float4 b4 = *reinterpret_cast<const float4*>(bproj + d0 + q * 4);
            floatx4 acc[4];
            #pragma unroll
            for (int mt = 0; mt < 4; ++mt) acc[mt] = (floatx4){b4.x, b4.y, b4.z, b4.w};
            #pragma unroll
            for (int s = 0; s < 6; ++s) {
                const short8 w8 = ldp((d0 + r) * DIM + s * 32 + q * 8);
                #pragma unroll
                for (int mt = 0; mt < 4; ++mt)      // swapped: D col=token, row=outdim
                    acc[mt] = __builtin_amdgcn_mfma_f32_16x16x32_bf16(w8, ao[mt][s], acc[mt], 0, 0, 0);
            }
            #pragma unroll
            for (int mt = 0; mt < 4; ++mt) {        // 4 consecutive dims -> float4 store
                float4 st;
                st.x = acc[mt][0]; st.y = acc[mt][1]; st.z = acc[mt][2]; st.w = acc[mt][3];
                *reinterpret_cast<float4*>(ob + (mt * 16 + r) * DIM + d0 + q * 4) = st;
            }
        }
        __syncthreads();   // osm/ksm/vsT/mlds reads done before next window overwrites
    }
}

extern "C" void kernel_launch(void* const* d_in, const int* in_sizes, int n_in,
                              void* d_out, int out_size, void* d_ws, size_t ws_size,
                              hipStream_t stream) {
    const float* x    = (const float*)d_in[0];
    const float* mask = (const float*)d_in[1];
    const float* wqkv = (const float*)d_in[2];
    const float* wp   = (const float*)d_in[3];
    const float* bp   = (const float*)d_in[4];
    float* out = (float*)d_out;
    const int nwin = in_sizes[0] / (NTOK * DIM);  // 4096 windows
    const int nblocks = nwin / W;                 // 512 blocks of 8 windows
    const size_t need = (size_t)(WQN + WPN) * sizeof(short);
    if (d_ws != nullptr && ws_size >= need) {
        short* wqb = (short*)d_ws;
        short* wpb = wqb + WQN;
        wprep<<<192, 256, 0, stream>>>(wqkv, wp, wqb, wpb);
        wattn_fused<1><<<nblocks, 256, 0, stream>>>(x, mask, wqkv, wp, bp, out, wqb, wpb);
    } else {
        wattn_fused<0><<<nblocks, 256, 0, stream>>>(x, mask, wqkv, wp, bp, out, nullptr, nullptr);
    }
}

// Round 5
// 713.520 us; speedup vs baseline: 1.3137x; 1.3137x over previous
//
#include <hip/hip_runtime.h>

#define NTOK 64
#define DIM 192
#define HD 32

// Padded global/LDS strides (bf16 elems):
//   RS=200 (100 dw == 4 mod 32): b128 reads 8 dw/bank (2-way, free).
//   VTS=68 (34 dw == 2 mod 32): b128 reads 8 dw/bank.
// Padding lives in the GLOBAL qkv workspace layout so kernel 2's linear
// blob copy into LDS reproduces the conflict-free layout directly.
#define RS   200
#define VTS  68
#define QBLK (NTOK * RS)            // 12800 shorts (q blob; k blob same)
#define VBLK (DIM * VTS)            // 13056 shorts (vT blob)
#define WBLOB (2 * QBLK + VBLK)     // 38656 shorts = 77312 B per window
#define WQN (576 * DIM)
#define WPN (DIM * DIM)

typedef __attribute__((ext_vector_type(8))) short short8;
typedef __attribute__((ext_vector_type(4))) float floatx4;
typedef __attribute__((ext_vector_type(2))) unsigned int uint2v;

__device__ __forceinline__ short f2bf(float f) {
    union { float f; unsigned int u; } c; c.f = f;
    unsigned int r = (c.u + 0x7FFFu + ((c.u >> 16) & 1u)) >> 16;
    return (short)(unsigned short)r;
}

// pack two fp32 -> two bf16 (RNE) in one dword: low16=bf(a), high16=bf(b)
__device__ __forceinline__ unsigned pkbf(float a, float b) {
    unsigned ua = __float_as_uint(a); ua += 0x7FFFu + ((ua >> 16) & 1u);
    unsigned ub = __float_as_uint(b); ub += 0x7FFFu + ((ub >> 16) & 1u);
    return __builtin_amdgcn_perm(ub, ua, 0x07060302u);
}

// 8 consecutive fp32 (16B-aligned) -> bf16x8 fragment (ascending k order)
__device__ __forceinline__ short8 cvt8(const float* p) {
    const float4* v = reinterpret_cast<const float4*>(p);
    float4 lo = v[0], hi = v[1];
    union { unsigned u[4]; short8 s; } r;
    r.u[0] = pkbf(lo.x, lo.y);
    r.u[1] = pkbf(lo.z, lo.w);
    r.u[2] = pkbf(hi.x, hi.y);
    r.u[3] = pkbf(hi.z, hi.w);
    return r.s;
}

// Quad-exchange: two MFMA-D-layout fp32 tiles (v0: rows 0..15, v1: rows 16..31;
// row = 16t + 4*quad + g, col = lane&15) -> bf16 A/B-fragment for K=32:
// lane (r,q) receives rows 8q+j (j=0..7), col r.
__device__ __forceinline__ short8 qshuf(floatx4 v0, floatx4 v1, int lane) {
    const int q = lane >> 4;
    const unsigned p0a = pkbf(v0[0], v0[1]);
    const unsigned p0b = pkbf(v0[2], v0[3]);
    const unsigned p1a = pkbf(v1[0], v1[1]);
    const unsigned p1b = pkbf(v1[2], v1[3]);
    const int s0 = (lane & 15) | ((q & 1) << 5);
    const int s1 = s0 + 16;
    const unsigned l0 = (unsigned)__shfl((int)p0a, s0);
    const unsigned h0 = (unsigned)__shfl((int)p1a, s0);
    const unsigned l1 = (unsigned)__shfl((int)p0b, s0);
    const unsigned h1 = (unsigned)__shfl((int)p1b, s0);
    const unsigned l2 = (unsigned)__shfl((int)p0a, s1);
    const unsigned h2 = (unsigned)__shfl((int)p1a, s1);
    const unsigned l3 = (unsigned)__shfl((int)p0b, s1);
    const unsigned h3 = (unsigned)__shfl((int)p1b, s1);
    const bool hi = q >= 2;
    union { unsigned u[4]; short8 s; } ret;
    ret.u[0] = hi ? h0 : l0;
    ret.u[1] = hi ? h1 : l1;
    ret.u[2] = hi ? h2 : l2;
    ret.u[3] = hi ? h3 : l3;
    return ret.s;
}

// One-time fp32 -> bf16 weight conversion (q rows get 1/sqrt(32) folded in).
__global__ void wprep(const float* __restrict__ wqkv, const float* __restrict__ wproj,
                      short* __restrict__ wqb, short* __restrict__ wpb) {
    const int i = blockIdx.x * 256 + (int)threadIdx.x;
    for (int e = i; e < WQN; e += 192 * 256) {
        float v = wqkv[e];
        if (e < DIM * DIM) v *= 0.17677669529663688f;
        wqb[e] = f2bf(v);
    }
    for (int e = i; e < WPN; e += 192 * 256) wpb[e] = f2bf(wproj[e]);
}

// ================= Kernel 1: QKV projection -> padded bf16 blobs =================
// One window per block. No LDS, no barriers — pure streaming GEMM shape.
// Per window blob: q [tok][dim] stride RS | k [tok][dim] stride RS | vT [dim][tok] stride VTS.
__global__ __launch_bounds__(256, 3)
void qkv_proj(const float* __restrict__ x, const short* __restrict__ wqb,
              short* __restrict__ qkv) {
    const int bw   = blockIdx.x;
    const int tid  = (int)threadIdx.x;
    const int wave = tid >> 6;
    const int lane = tid & 63;
    const int r    = lane & 15;
    const int q    = lane >> 4;

    const float* xb = x + (size_t)bw * (NTOK * DIM);
    short* qb = qkv + (size_t)bw * WBLOB;
    short* kb = qb + QBLK;
    short* vb = kb + QBLK;

    short8 a[4][6];   // full X in regs (lane r = token, k = s*32 + q*8 + j)
    #pragma unroll
    for (int mt = 0; mt < 4; ++mt) {
        #pragma unroll
        for (int s = 0; s < 6; ++s)
            a[mt][s] = cvt8(xb + (mt * 16 + r) * DIM + s * 32 + q * 8);
    }

    #pragma unroll 1
    for (int nt = 0; nt < 9; ++nt) {
        const int d0 = wave * 144 + nt * 16;   // output column tile (wave-uniform)
        floatx4 acc[4];
        #pragma unroll
        for (int mt = 0; mt < 4; ++mt) acc[mt] = (floatx4){0.f, 0.f, 0.f, 0.f};
        if (d0 < 2 * DIM) {
            // q/k: swapped orientation -> D col=token(r), row=dim(4q+g)
            #pragma unroll
            for (int s = 0; s < 6; ++s) {
                const short8 b8 = *reinterpret_cast<const short8*>(
                    wqb + (d0 + r) * DIM + s * 32 + q * 8);
                #pragma unroll
                for (int mt = 0; mt < 4; ++mt)
                    acc[mt] = __builtin_amdgcn_mfma_f32_16x16x32_bf16(b8, a[mt][s], acc[mt], 0, 0, 0);
            }
            short* dst = (d0 < DIM) ? qb : kb;
            const int dc = (d0 < DIM) ? d0 : d0 - DIM;
            #pragma unroll
            for (int mt = 0; mt < 4; ++mt) {   // 4 consecutive dims -> one b64 store
                uint2v u;
                u.x = pkbf(acc[mt][0], acc[mt][1]);
                u.y = pkbf(acc[mt][2], acc[mt][3]);
                *reinterpret_cast<uint2v*>(dst + (mt * 16 + r) * RS + dc + q * 4) = u;
            }
        } else {
            // v: normal orientation -> D col=vdim(r), row=token(4q+g); vT dim-major
            const int dv = d0 - 2 * DIM;
            #pragma unroll
            for (int s = 0; s < 6; ++s) {
                const short8 b8 = *reinterpret_cast<const short8*>(
                    wqb + (d0 + r) * DIM + s * 32 + q * 8);
                #pragma unroll
                for (int mt = 0; mt < 4; ++mt)
                    acc[mt] = __builtin_amdgcn_mfma_f32_16x16x32_bf16(a[mt][s], b8, acc[mt], 0, 0, 0);
            }
            #pragma unroll
            for (int mt = 0; mt < 4; ++mt) {   // 4 consecutive tokens -> one b64 store
                uint2v u;
                u.x = pkbf(acc[mt][0], acc[mt][1]);
                u.y = pkbf(acc[mt][2], acc[mt][3]);
                *reinterpret_cast<uint2v*>(vb + (dv + r) * VTS + mt * 16 + q * 4) = u;
            }
        }
    }
}

// ================= Kernel 2: attention + output projection =================
// One window per block. Blob copied linearly into LDS (padded layouts preserved),
// then r3's verified phase-2/3. Q read directly as B-fragments (no Q-GEMM).
__global__ __launch_bounds__(256, 2)
void attn_out(const short* __restrict__ qkv, const float* __restrict__ mask,
              const short* __restrict__ wpb, const float* __restrict__ bproj,
              float* __restrict__ out) {
    __shared__ short blob[38912];   // q[0,12800) k[12800,25600) vT[25600,38656) scrap[..38912)

    const int bw   = blockIdx.x;
    const int tid  = (int)threadIdx.x;
    const int wave = tid >> 6;
    const int lane = tid & 63;
    const int r    = lane & 15;
    const int q    = lane >> 4;

    // linear coalesced copy: 19 x 16B per thread (reads 512B of pad at array tail)
    const short* src = qkv + (size_t)bw * WBLOB;
    #pragma unroll
    for (int j = 0; j < 19; ++j) {
        const int o = (tid + 256 * j) * 8;
        *reinterpret_cast<short8*>(blob + o) = *reinterpret_cast<const short8*>(src + o);
    }
    __syncthreads();

    short* ksm = blob + QBLK;
    short* vsT = blob + 2 * QBLK;

    // Q^T B-fragments straight from LDS (lane r = query, k = qdim)
    short8 bq[3][2];
    #pragma unroll
    for (int i = 0; i < 3; ++i) {
        const int uu = wave * 3 + i, h = uu >> 1, half = uu & 1;
        #pragma unroll
        for (int qt = 0; qt < 2; ++qt)
            bq[i][qt] = *reinterpret_cast<const short8*>(
                blob + (half * 32 + qt * 16 + r) * RS + h * HD + q * 8);
    }
    __syncthreads();   // q region consumed -> becomes osm
    short* osm = blob;

    const float* mbl = mask + (size_t)bw * (NTOK * NTOK) + 256 * q + r;

    #pragma unroll
    for (int i = 0; i < 3; ++i) {
        const int uu = wave * 3 + i, h = uu >> 1, half = uu & 1;

        // mask loads issued early (mask symmetric: read [key][query], coalesced)
        float mv[2][4][4];
        #pragma unroll
        for (int qt = 0; qt < 2; ++qt)
            #pragma unroll
            for (int kt = 0; kt < 4; ++kt)
                #pragma unroll
                for (int g = 0; g < 4; ++g)
                    mv[qt][kt][g] = mbl[kt * 1024 + g * 64 + half * 32 + qt * 16];

        short8 bk[4];
        #pragma unroll
        for (int kt = 0; kt < 4; ++kt)
            bk[kt] = *reinterpret_cast<const short8*>(ksm + (kt * 16 + r) * RS + h * HD + q * 8);

        // S^T = mfma(K, Q): lane col=query (r), row=key (kt*16 + q*4+g)
        floatx4 sa[4][2];
        #pragma unroll
        for (int kt = 0; kt < 4; ++kt) {
            floatx4 z = (floatx4){0.f, 0.f, 0.f, 0.f};
            sa[kt][0] = __builtin_amdgcn_mfma_f32_16x16x32_bf16(bk[kt], bq[i][0], z, 0, 0, 0);
            sa[kt][1] = __builtin_amdgcn_mfma_f32_16x16x32_bf16(bk[kt], bq[i][1], z, 0, 0, 0);
        }
        #pragma unroll
        for (int kt = 0; kt < 4; ++kt)
            #pragma unroll
            for (int qt = 0; qt < 2; ++qt)
                #pragma unroll
                for (int g = 0; g < 4; ++g)
                    sa[kt][qt][g] += mv[qt][kt][g];

        // softmax: 16 in-lane + 2 cross-quad shuffles
        float rinv[2];
        #pragma unroll
        for (int qt = 0; qt < 2; ++qt) {
            float mx = sa[0][qt][0];
            #pragma unroll
            for (int kt = 0; kt < 4; ++kt)
                #pragma unroll
                for (int g = 0; g < 4; ++g) mx = fmaxf(mx, sa[kt][qt][g]);
            mx = fmaxf(mx, __shfl_xor(mx, 16));
            mx = fmaxf(mx, __shfl_xor(mx, 32));
            float sm = 0.f;
            #pragma unroll
            for (int kt = 0; kt < 4; ++kt) {
                #pragma unroll
                for (int g = 0; g < 4; ++g) {
                    float p = __expf(sa[kt][qt][g] - mx);
                    sa[kt][qt][g] = p;
                    sm += p;
                }
            }
            sm += __shfl_xor(sm, 16);
            sm += __shfl_xor(sm, 32);
            rinv[qt] = 1.0f / sm;   // normalization deferred to O
        }

        // P fragments in-register
        short8 ap[2][2];
        #pragma unroll
        for (int qt = 0; qt < 2; ++qt) {
            #pragma unroll
            for (int kk = 0; kk < 2; ++kk)
                ap[qt][kk] = qshuf(sa[2 * kk][qt], sa[2 * kk + 1][qt], lane);
        }

        short8 bv[2][2];
        #pragma unroll
        for (int nv = 0; nv < 2; ++nv)
            #pragma unroll
            for (int kk = 0; kk < 2; ++kk)
                bv[nv][kk] = *reinterpret_cast<const short8*>(
                    vsT + (h * HD + nv * 16 + r) * VTS + kk * 32 + q * 8);

        // O^T = mfma(V^T, P^T): lane col=query (r) -> rinv lane-local; -> osm
        #pragma unroll
        for (int qt = 0; qt < 2; ++qt) {
            #pragma unroll
            for (int nv = 0; nv < 2; ++nv) {
                floatx4 o = (floatx4){0.f, 0.f, 0.f, 0.f};
                o = __builtin_amdgcn_mfma_f32_16x16x32_bf16(bv[nv][0], ap[qt][0], o, 0, 0, 0);
                o = __builtin_amdgcn_mfma_f32_16x16x32_bf16(bv[nv][1], ap[qt][1], o, 0, 0, 0);
                uint2v u;
                u.x = pkbf(o[0] * rinv[qt], o[1] * rinv[qt]);
                u.y = pkbf(o[2] * rinv[qt], o[3] * rinv[qt]);
                *reinterpret_cast<uint2v*>(
                    osm + (half * 32 + qt * 16 + r) * RS + h * HD + nv * 16 + q * 4) = u;
            }
        }
    }
    __syncthreads();   // osm complete

    // out = O * Wproj^T + b
    short8 ao[4][6];
    #pragma unroll
    for (int mt = 0; mt < 4; ++mt) {
        #pragma unroll
        for (int s = 0; s < 6; ++s)
            ao[mt][s] = *reinterpret_cast<const short8*>(osm + (mt * 16 + r) * RS + s * 32 + q * 8);
    }

    float* ob = out + (size_t)bw * (NTOK * DIM);
    #pragma unroll
    for (int nt = 0; nt < 3; ++nt) {
        const int d0 = wave * 48 + nt * 16;
        const float4 b4 = *reinterpret_cast<const float4*>(bproj + d0 + q * 4);
        floatx4 acc[4];
        #pragma unroll
        for (int mt = 0; mt < 4; ++mt) acc[mt] = (floatx4){b4.x, b4.y, b4.z, b4.w};
        #pragma unroll
        for (int s = 0; s < 6; ++s) {
            const short8 w8 = *reinterpret_cast<const short8*>(wpb + (d0 + r) * DIM + s * 32 + q * 8);
            #pragma unroll
            for (int mt = 0; mt < 4; ++mt)      // swapped: D col=token, row=outdim
                acc[mt] = __builtin_amdgcn_mfma_f32_16x16x32_bf16(w8, ao[mt][s], acc[mt], 0, 0, 0);
        }
        #pragma unroll
        for (int mt = 0; mt < 4; ++mt) {
            float4 st;
            st.x = acc[mt][0]; st.y = acc[mt][1]; st.z = acc[mt][2]; st.w = acc[mt][3];
            *reinterpret_cast<float4*>(ob + (mt * 16 + r) * DIM + d0 + q * 4) = st;
        }
    }
}

// ================= Fallback: round-3 fused kernel (verified) =================
template <int WS>
__global__ __launch_bounds__(256, 2)
void wattn_fused(const float* __restrict__ x, const float* __restrict__ mask,
                 const float* __restrict__ wqkv, const float* __restrict__ wproj,
                 const float* __restrict__ bproj, float* __restrict__ out,
                 const short* __restrict__ wqb, const short* __restrict__ wpb) {
    __shared__ short ksm[NTOK * RS];
    __shared__ short vsT[DIM * VTS];
    __shared__ short osm[NTOK * RS];

    const int bw   = blockIdx.x;
    const int tid  = (int)threadIdx.x;
    const int wave = tid >> 6;
    const int lane = tid & 63;
    const int r    = lane & 15;
    const int q    = lane >> 4;

    const float* xb = x + (size_t)bw * (NTOK * DIM);

    auto ldq = [&](int off) -> short8 {
        if constexpr (WS) return *reinterpret_cast<const short8*>(wqb + off);
        else              return cvt8(wqkv + off);
    };
    auto ldp = [&](int off) -> short8 {
        if constexpr (WS) return *reinterpret_cast<const short8*>(wpb + off);
        else              return cvt8(wproj + off);
    };

    {
        short8 a[4][6];
        #pragma unroll
        for (int mt = 0; mt < 4; ++mt) {
            #pragma unroll
            for (int s = 0; s < 6; ++s)
                a[mt][s] = cvt8(xb + (mt * 16 + r) * DIM + s * 32 + q * 8);
        }
        if (wave < 2) {
            #pragma unroll 1
            for (int nt = 0; nt < 6; ++nt) {
                const int dk = wave * 96 + nt * 16;
                floatx4 acc[4];
                #pragma unroll
                for (int mt = 0; mt < 4; ++mt) acc[mt] = (floatx4){0.f, 0.f, 0.f, 0.f};
                #pragma unroll
                for (int s = 0; s < 6; ++s) {
                    const short8 b8 = ldq((DIM + dk + r) * DIM + s * 32 + q * 8);
                    #pragma unroll
                    for (int mt = 0; mt < 4; ++mt)
                        acc[mt] = __builtin_amdgcn_mfma_f32_16x16x32_bf16(b8, a[mt][s], acc[mt], 0, 0, 0);
                }
                #pragma unroll
                for (int mt = 0; mt < 4; ++mt) {
                    uint2v u;
                    u.x = pkbf(acc[mt][0], acc[mt][1]);
                    u.y = pkbf(acc[mt][2], acc[mt][3]);
                    *reinterpret_cast<uint2v*>(ksm + (mt * 16 + r) * RS + dk + q * 4) = u;
                }
            }
        } else {
            #pragma unroll 1
            for (int nt = 0; nt < 6; ++nt) {
                const int dv = (wave - 2) * 96 + nt * 16;
                floatx4 acc[4];
                #pragma unroll
                for (int mt = 0; mt < 4; ++mt) acc[mt] = (floatx4){0.f, 0.f, 0.f, 0.f};
                #pragma unroll
                for (int s = 0; s < 6; ++s) {
                    const short8 b8 = ldq((2 * DIM + dv + r) * DIM + s * 32 + q * 8);
                    #pragma unroll
                    for (int mt = 0; mt < 4; ++mt)
                        acc[mt] = __builtin_amdgcn_mfma_f32_16x16x32_bf16(a[mt][s], b8, acc[mt], 0, 0, 0);
                }
                #pragma unroll
                for (int mt = 0; mt < 4; ++mt) {
                    uint2v u;
                    u.x = pkbf(acc[mt][0], acc[mt][1]);
                    u.y = pkbf(acc[mt][2], acc[mt][3]);
                    *reinterpret_cast<uint2v*>(vsT + (dv + r) * VTS + mt * 16 + q * 4) = u;
                }
            }
        }
    }
    __builtin_amdgcn_sched_barrier(0);
    __syncthreads();

    const float* mbl = mask + (size_t)bw * (NTOK * NTOK) + 256 * q + r;

    #pragma unroll 1
    for (int i = 0; i < 3; ++i) {
        const int uu = wave * 3 + i, h = uu >> 1, half = uu & 1;
        float mv[2][4][4];
        #pragma unroll
        for (int qt = 0; qt < 2; ++qt)
            #pragma unroll
            for (int kt = 0; kt < 4; ++kt)
                #pragma unroll
                for (int g = 0; g < 4; ++g)
                    mv[qt][kt][g] = mbl[kt * 1024 + g * 64 + half * 32 + qt * 16];

        floatx4 qa[2][2];
        #pragma unroll
        for (int dt = 0; dt < 2; ++dt)
            #pragma unroll
            for (int qt = 0; qt < 2; ++qt) qa[dt][qt] = (floatx4){0.f, 0.f, 0.f, 0.f};
        #pragma unroll
        for (int s = 0; s < 6; ++s) {
            const short8 w0 = ldq((h * HD + r) * DIM + s * 32 + q * 8);
            const short8 w1 = ldq((h * HD + 16 + r) * DIM + s * 32 + q * 8);
            #pragma unroll
            for (int qt = 0; qt < 2; ++qt) {
                const short8 xf = cvt8(xb + ((half * 2 + qt) * 16 + r) * DIM + s * 32 + q * 8);
                qa[0][qt] = __builtin_amdgcn_mfma_f32_16x16x32_bf16(w0, xf, qa[0][qt], 0, 0, 0);
                qa[1][qt] = __builtin_amdgcn_mfma_f32_16x16x32_bf16(w1, xf, qa[1][qt], 0, 0, 0);
            }
        }
        if constexpr (!WS) {
            #pragma unroll
            for (int dt = 0; dt < 2; ++dt)
                #pragma unroll
                for (int qt = 0; qt < 2; ++qt)
                    #pragma unroll
                    for (int g = 0; g < 4; ++g)
                        qa[dt][qt][g] *= 0.17677669529663688f;
        }
        short8 bq0 = qshuf(qa[0][0], qa[1][0], lane);
        short8 bq1 = qshuf(qa[0][1], qa[1][1], lane);

        short8 bk[4];
        #pragma unroll
        for (int kt = 0; kt < 4; ++kt)
            bk[kt] = *reinterpret_cast<const short8*>(ksm + (kt * 16 + r) * RS + h * HD + q * 8);

        floatx4 sa[4][2];
        #pragma unroll
        for (int kt = 0; kt < 4; ++kt) {
            floatx4 z = (floatx4){0.f, 0.f, 0.f, 0.f};
            sa[kt][0] = __builtin_amdgcn_mfma_f32_16x16x32_bf16(bk[kt], bq0, z, 0, 0, 0);
            sa[kt][1] = __builtin_amdgcn_mfma_f32_16x16x32_bf16(bk[kt], bq1, z, 0, 0, 0);
        }
        #pragma unroll
        for (int kt = 0; kt < 4; ++kt)
            #pragma unroll
            for (int qt = 0; qt < 2; ++qt)
                #pragma unroll
                for (int g = 0; g < 4; ++g)
                    sa[kt][qt][g] += mv[qt][kt][g];

        float rinv[2];
        #pragma unroll
        for (int qt = 0; qt < 2; ++qt) {
            float mx = sa[0][qt][0];
            #pragma unroll
            for (int kt = 0; kt < 4; ++kt)
                #pragma unroll
                for (int g = 0; g < 4; ++g) mx = fmaxf(mx, sa[kt][qt][g]);
            mx = fmaxf(mx, __shfl_xor(mx, 16));
            mx = fmaxf(mx, __shfl_xor(mx, 32));
            float sm = 0.f;
            #pragma unroll
            for (int kt = 0; kt < 4; ++kt) {
                #pragma unroll
                for (int g = 0; g < 4; ++g) {
                    float p = __expf(sa[kt][qt][g] - mx);
                    sa[kt][qt][g] = p;
                    sm += p;
                }
            }
            sm += __shfl_xor(sm, 16);
            sm += __shfl_xor(sm, 32);
            rinv[qt] = 1.0f / sm;
        }

        short8 ap[2][2];
        #pragma unroll
        for (int qt = 0; qt < 2; ++qt) {
            #pragma unroll
            for (int kk = 0; kk < 2; ++kk)
                ap[qt][kk] = qshuf(sa[2 * kk][qt], sa[2 * kk + 1][qt], lane);
        }

        short8 bv[2][2];
        #pragma unroll
        for (int nv = 0; nv < 2; ++nv)
            #pragma unroll
            for (int kk = 0; kk < 2; ++kk)
                bv[nv][kk] = *reinterpret_cast<const short8*>(
                    vsT + (h * HD + nv * 16 + r) * VTS + kk * 32 + q * 8);

        #pragma unroll
        for (int qt = 0; qt < 2; ++qt) {
            #pragma unroll
            for (int nv = 0; nv < 2; ++nv) {
                floatx4 o = (floatx4){0.f, 0.f, 0.f, 0.f};
                o = __builtin_amdgcn_mfma_f32_16x16x32_bf16(bv[nv][0], ap[qt][0], o, 0, 0, 0);
                o = __builtin_amdgcn_mfma_f32_16x16x32_bf16(bv[nv][1], ap[qt][1], o, 0, 0, 0);
                uint2v u;
                u.x = pkbf(o[0] * rinv[qt], o[1] * rinv[qt]);
                u.y = pkbf(o[2] * rinv[qt], o[3] * rinv[qt]);
                *reinterpret_cast<uint2v*>(
                    osm + (half * 32 + qt * 16 + r) * RS + h * HD + nv * 16 + q * 4) = u;
            }
        }
    }
    __syncthreads();

    short8 ao[4][6];
    #pragma unroll
    for (int mt = 0; mt < 4; ++mt) {
        #pragma unroll
        for (int s = 0; s < 6; ++s)
            ao[mt][s] = *reinterpret_cast<const short8*>(osm + (mt * 16 + r) * RS + s * 32 + q * 8);
    }

    float* ob = out + (size_t)bw * (NTOK * DIM);
    #pragma unroll 1
    for (int nt = 0; nt < 3; ++nt) {
        const int d0 = wave * 48 + nt * 16;
        const float4 b4 = *reinterpret_cast<const float4*>(bproj + d0 + q * 4);
        floatx4 acc[4];
        #pragma unroll
        for (int mt = 0; mt < 4; ++mt) acc[mt] = (floatx4){b4.x, b4.y, b4.z, b4.w};
        #pragma unroll
        for (int s = 0; s < 6; ++s) {
            const short8 w8 = ldp((d0 + r) * DIM + s * 32 + q * 8);
            #pragma unroll
            for (int mt = 0; mt < 4; ++mt)
                acc[mt] = __builtin_amdgcn_mfma_f32_16x16x32_bf16(w8, ao[mt][s], acc[mt], 0, 0, 0);
        }
        #pragma unroll
        for (int mt = 0; mt < 4; ++mt) {
            float4 st;
            st.x = acc[mt][0]; st.y = acc[mt][1]; st.z = acc[mt][2]; st.w = acc[mt][3];
            *reinterpret_cast<float4*>(ob + (mt * 16 + r) * DIM + d0 + q * 4) = st;
        }
    }
}

extern "C" void kernel_launch(void* const* d_in, const int* in_sizes, int n_in,
                              void* d_out, int out_size, void* d_ws, size_t ws_size,
                              hipStream_t stream) {
    const float* x    = (const float*)d_in[0];
    const float* mask = (const float*)d_in[1];
    const float* wqkv = (const float*)d_in[2];
    const float* wp   = (const float*)d_in[3];
    const float* bp   = (const float*)d_in[4];
    float* out = (float*)d_out;
    const int nwin = in_sizes[0] / (NTOK * DIM);   // 4096 windows

    const size_t needw     = (size_t)(WQN + WPN) * sizeof(short);
    const size_t needsplit = needw + ((size_t)nwin * WBLOB + 256) * sizeof(short);

    if (d_ws != nullptr && ws_size >= needsplit) {
        short* wqb  = (short*)d_ws;
        short* wpb  = wqb + WQN;
        short* qkvb = wpb + WPN;
        wprep<<<192, 256, 0, stream>>>(wqkv, wp, wqb, wpb);
        qkv_proj<<<nwin, 256, 0, stream>>>(x, wqb, qkvb);
        attn_out<<<nwin, 256, 0, stream>>>(qkvb, mask, wpb, bp, out);
    } else if (d_ws != nullptr && ws_size >= needw) {
        short* wqb = (short*)d_ws;
        short* wpb = wqb + WQN;
        wprep<<<192, 256, 0, stream>>>(wqkv, wp, wqb, wpb);
        wattn_fused<1><<<nwin, 256, 0, stream>>>(x, mask, wqkv, wp, bp, out, wqb, wpb);
    } else {
        wattn_fused<0><<<nwin, 256, 0, stream>>>(x, mask, wqkv, wp, bp, out, nullptr, nullptr);
    }
}

// Round 6
// 681.817 us; speedup vs baseline: 1.3748x; 1.0465x over previous
//
#include <hip/hip_runtime.h>

#define NTOK 64
#define DIM 192
#define HD 32

// LDS strides (bf16 elems):
//   RS=200 (100 dw == 4 mod 32): b128 reads 8 dw/bank; b64 writes 4 dw/bank.
//   VTS=68 (34 dw == 2 mod 32): b128 reads 8 dw/bank; b64 writes 4 dw/bank.
// LDS = ksm 25600 + vsT 26112 + osm 25600 = 77312 B -> 2 blocks/CU.
#define RS  200
#define VTS 68
#define WQN (576 * DIM)
#define WPN (DIM * DIM)

typedef __attribute__((ext_vector_type(8))) short short8;
typedef __attribute__((ext_vector_type(4))) float floatx4;
typedef __attribute__((ext_vector_type(2))) unsigned int uint2v;

__device__ __forceinline__ short f2bf(float f) {
    union { float f; unsigned int u; } c; c.f = f;
    unsigned int r = (c.u + 0x7FFFu + ((c.u >> 16) & 1u)) >> 16;
    return (short)(unsigned short)r;
}

// pack two fp32 -> two bf16 (RNE) in one dword: low16=bf(a), high16=bf(b)
__device__ __forceinline__ unsigned pkbf(float a, float b) {
    unsigned ua = __float_as_uint(a); ua += 0x7FFFu + ((ua >> 16) & 1u);
    unsigned ub = __float_as_uint(b); ub += 0x7FFFu + ((ub >> 16) & 1u);
    return __builtin_amdgcn_perm(ub, ua, 0x07060302u);
}

// 8 consecutive fp32 (16B-aligned) -> bf16x8 fragment (ascending k order)
__device__ __forceinline__ short8 cvt8(const float* p) {
    const float4* v = reinterpret_cast<const float4*>(p);
    float4 lo = v[0], hi = v[1];
    union { unsigned u[4]; short8 s; } r;
    r.u[0] = pkbf(lo.x, lo.y);
    r.u[1] = pkbf(lo.z, lo.w);
    r.u[2] = pkbf(hi.x, hi.y);
    r.u[3] = pkbf(hi.z, hi.w);
    return r.s;
}

// Quad-exchange: two MFMA-D-layout fp32 tiles (v0: rows 0..15, v1: rows 16..31;
// row = 16t + 4*quad + g, col = lane&15) -> bf16 A/B-fragment for K=32:
// lane (r,q) receives rows 8q+j (j=0..7), col r.
__device__ __forceinline__ short8 qshuf(floatx4 v0, floatx4 v1, int lane) {
    const int q = lane >> 4;
    const unsigned p0a = pkbf(v0[0], v0[1]);
    const unsigned p0b = pkbf(v0[2], v0[3]);
    const unsigned p1a = pkbf(v1[0], v1[1]);
    const unsigned p1b = pkbf(v1[2], v1[3]);
    const int s0 = (lane & 15) | ((q & 1) << 5);
    const int s1 = s0 + 16;
    const unsigned l0 = (unsigned)__shfl((int)p0a, s0);
    const unsigned h0 = (unsigned)__shfl((int)p1a, s0);
    const unsigned l1 = (unsigned)__shfl((int)p0b, s0);
    const unsigned h1 = (unsigned)__shfl((int)p1b, s0);
    const unsigned l2 = (unsigned)__shfl((int)p0a, s1);
    const unsigned h2 = (unsigned)__shfl((int)p1a, s1);
    const unsigned l3 = (unsigned)__shfl((int)p0b, s1);
    const unsigned h3 = (unsigned)__shfl((int)p1b, s1);
    const bool hi = q >= 2;
    union { unsigned u[4]; short8 s; } ret;
    ret.u[0] = hi ? h0 : l0;
    ret.u[1] = hi ? h1 : l1;
    ret.u[2] = hi ? h2 : l2;
    ret.u[3] = hi ? h3 : l3;
    return ret.s;
}

// One-time fp32 -> bf16 weight conversion (q rows get 1/sqrt(32) folded in).
__global__ void wprep(const float* __restrict__ wqkv, const float* __restrict__ wproj,
                      short* __restrict__ wqb, short* __restrict__ wpb) {
    const int i = blockIdx.x * 256 + (int)threadIdx.x;
    for (int e = i; e < WQN; e += 192 * 256) {
        float v = wqkv[e];
        if (e < DIM * DIM) v *= 0.17677669529663688f;
        wqb[e] = f2bf(v);
    }
    for (int e = i; e < WPN; e += 192 * 256) wpb[e] = f2bf(wproj[e]);
}

template <int WS>
__global__ __launch_bounds__(256, 2)
void wattn_fused(const float* __restrict__ x, const float* __restrict__ mask,
                 const float* __restrict__ wqkv, const float* __restrict__ wproj,
                 const float* __restrict__ bproj, float* __restrict__ out,
                 const short* __restrict__ wqb, const short* __restrict__ wpb) {
    __shared__ short ksm[NTOK * RS];   // K  [token][kdim]
    __shared__ short vsT[DIM * VTS];   // V^T[vdim][token]
    __shared__ short osm[NTOK * RS];   // O  [token][outdim]

    const int bw   = blockIdx.x;
    const int tid  = (int)threadIdx.x;
    const int wave = tid >> 6;
    const int lane = tid & 63;
    const int r    = lane & 15;
    const int q    = lane >> 4;

    const float* xb = x + (size_t)bw * (NTOK * DIM);

    auto ldq = [&](int off) -> short8 {
        if constexpr (WS) return *reinterpret_cast<const short8*>(wqb + off);
        else              return cvt8(wqkv + off);
    };
    auto ldp = [&](int off) -> short8 {
        if constexpr (WS) return *reinterpret_cast<const short8*>(wpb + off);
        else              return cvt8(wproj + off);
    };

    // ---------------- Phase 1a: K (waves 0,1) / V (waves 2,3) -> LDS ----------------
    // X fragments scoped here: their 96 VGPRs die at the end of this block and
    // are re-spent on the 96 prefetched mask values below (budget-neutral).
    {
        short8 a[4][6];   // lane r = token, k = s*32 + q*8 + j
        #pragma unroll
        for (int mt = 0; mt < 4; ++mt) {
            #pragma unroll
            for (int s = 0; s < 6; ++s)
                a[mt][s] = cvt8(xb + (mt * 16 + r) * DIM + s * 32 + q * 8);
        }

        if (wave < 2) {
            #pragma unroll 1
            for (int nt = 0; nt < 6; ++nt) {
                const int dk = wave * 96 + nt * 16;
                floatx4 acc[4];
                #pragma unroll
                for (int mt = 0; mt < 4; ++mt) acc[mt] = (floatx4){0.f, 0.f, 0.f, 0.f};
                #pragma unroll
                for (int s = 0; s < 6; ++s) {
                    const short8 b8 = ldq((DIM + dk + r) * DIM + s * 32 + q * 8);
                    #pragma unroll
                    for (int mt = 0; mt < 4; ++mt)  // swapped: D col=token, row=kdim
                        acc[mt] = __builtin_amdgcn_mfma_f32_16x16x32_bf16(b8, a[mt][s], acc[mt], 0, 0, 0);
                }
                #pragma unroll
                for (int mt = 0; mt < 4; ++mt) {    // 4 consecutive kdims -> one b64 store
                    uint2v u;
                    u.x = pkbf(acc[mt][0], acc[mt][1]);
                    u.y = pkbf(acc[mt][2], acc[mt][3]);
                    *reinterpret_cast<uint2v*>(ksm + (mt * 16 + r) * RS + dk + q * 4) = u;
                }
            }
        } else {
            #pragma unroll 1
            for (int nt = 0; nt < 6; ++nt) {
                const int dv = (wave - 2) * 96 + nt * 16;
                floatx4 acc[4];
                #pragma unroll
                for (int mt = 0; mt < 4; ++mt) acc[mt] = (floatx4){0.f, 0.f, 0.f, 0.f};
                #pragma unroll
                for (int s = 0; s < 6; ++s) {
                    const short8 b8 = ldq((2 * DIM + dv + r) * DIM + s * 32 + q * 8);
                    #pragma unroll
                    for (int mt = 0; mt < 4; ++mt)  // normal: D col=vdim, row=token
                        acc[mt] = __builtin_amdgcn_mfma_f32_16x16x32_bf16(a[mt][s], b8, acc[mt], 0, 0, 0);
                }
                #pragma unroll
                for (int mt = 0; mt < 4; ++mt) {    // 4 consecutive tokens -> one b64 store
                    uint2v u;
                    u.x = pkbf(acc[mt][0], acc[mt][1]);
                    u.y = pkbf(acc[mt][2], acc[mt][3]);
                    *reinterpret_cast<uint2v*>(vsT + (dv + r) * VTS + mt * 16 + q * 4) = u;
                }
            }
        }
    }
    // Pin: phase-1b/2 code must not hoist above (keeps a[][] dead -> no spill).
    __builtin_amdgcn_sched_barrier(0);

    // ---------------- Mask prefetch: ALL 96 loads issued in one cluster ----------------
    // One latency exposure for all 3 units instead of 3 serial per-unit clusters
    // on the softmax critical path. Latency hides under phase 1b + barrier.
    const float* mbl = mask + (size_t)bw * (NTOK * NTOK) + 256 * q + r;
    float mv[3][2][4][4];
    #pragma unroll
    for (int u = 0; u < 3; ++u) {
        const int half = (wave * 3 + u) & 1;
        #pragma unroll
        for (int qt = 0; qt < 2; ++qt)
            #pragma unroll
            for (int kt = 0; kt < 4; ++kt)
                #pragma unroll
                for (int g = 0; g < 4; ++g)
                    mv[u][qt][kt][g] = mbl[kt * 1024 + g * 64 + half * 32 + qt * 16];
    }
    // Pin: loads may not sink into phase 2 (compiler would re-serialize them).
    __builtin_amdgcn_sched_barrier(0);

    // ---------------- Phase 1b: Q per unit -> B-fragments in registers ----------------
    // X re-fetched from global (L1/L2-hot, proven cheap in r2/r3).
    short8 bq[3][2];
    #pragma unroll
    for (int u = 0; u < 3; ++u) {
        const int uu = wave * 3 + u, h = uu >> 1, half = uu & 1;
        floatx4 qa[2][2];
        #pragma unroll
        for (int dt = 0; dt < 2; ++dt)
            #pragma unroll
            for (int qt = 0; qt < 2; ++qt) qa[dt][qt] = (floatx4){0.f, 0.f, 0.f, 0.f};
        #pragma unroll
        for (int s = 0; s < 6; ++s) {
            const short8 w0 = ldq((h * HD + r) * DIM + s * 32 + q * 8);
            const short8 w1 = ldq((h * HD + 16 + r) * DIM + s * 32 + q * 8);
            #pragma unroll
            for (int qt = 0; qt < 2; ++qt) {    // swapped: D col=token, row=qdim
                const short8 xf = cvt8(xb + ((half * 2 + qt) * 16 + r) * DIM + s * 32 + q * 8);
                qa[0][qt] = __builtin_amdgcn_mfma_f32_16x16x32_bf16(w0, xf, qa[0][qt], 0, 0, 0);
                qa[1][qt] = __builtin_amdgcn_mfma_f32_16x16x32_bf16(w1, xf, qa[1][qt], 0, 0, 0);
            }
        }
        if constexpr (!WS) {
            #pragma unroll
            for (int dt = 0; dt < 2; ++dt)
                #pragma unroll
                for (int qt = 0; qt < 2; ++qt)
                    #pragma unroll
                    for (int g = 0; g < 4; ++g)
                        qa[dt][qt][g] *= 0.17677669529663688f;
        }
        bq[u][0] = qshuf(qa[0][0], qa[1][0], lane);  // lane r=query, k=head dim
        bq[u][1] = qshuf(qa[0][1], qa[1][1], lane);
    }
    __syncthreads();   // K/V staged; mask already in regs

    // ---------------- Phase 2: attention, pure LDS + MFMA + VALU ----------------
    #pragma unroll
    for (int u = 0; u < 3; ++u) {
        const int uu = wave * 3 + u, h = uu >> 1, half = uu & 1;

        short8 bk[4];
        #pragma unroll
        for (int kt = 0; kt < 4; ++kt)
            bk[kt] = *reinterpret_cast<const short8*>(ksm + (kt * 16 + r) * RS + h * HD + q * 8);

        // S^T = mfma(K, Q): lane col=query (r), row=key (kt*16 + q*4+g)
        floatx4 sa[4][2];
        #pragma unroll
        for (int kt = 0; kt < 4; ++kt) {
            floatx4 z = (floatx4){0.f, 0.f, 0.f, 0.f};
            sa[kt][0] = __builtin_amdgcn_mfma_f32_16x16x32_bf16(bk[kt], bq[u][0], z, 0, 0, 0);
            sa[kt][1] = __builtin_amdgcn_mfma_f32_16x16x32_bf16(bk[kt], bq[u][1], z, 0, 0, 0);
        }
        #pragma unroll
        for (int kt = 0; kt < 4; ++kt)
            #pragma unroll
            for (int qt = 0; qt < 2; ++qt)
                #pragma unroll
                for (int g = 0; g < 4; ++g)
                    sa[kt][qt][g] += mv[u][qt][kt][g];

        // softmax: 16 in-lane + 2 cross-quad shuffles (keys live on quads)
        float rinv[2];
        #pragma unroll
        for (int qt = 0; qt < 2; ++qt) {
            float mx = sa[0][qt][0];
            #pragma unroll
            for (int kt = 0; kt < 4; ++kt)
                #pragma unroll
                for (int g = 0; g < 4; ++g) mx = fmaxf(mx, sa[kt][qt][g]);
            mx = fmaxf(mx, __shfl_xor(mx, 16));
            mx = fmaxf(mx, __shfl_xor(mx, 32));
            float sm = 0.f;
            #pragma unroll
            for (int kt = 0; kt < 4; ++kt) {
                #pragma unroll
                for (int g = 0; g < 4; ++g) {
                    float p = __expf(sa[kt][qt][g] - mx);
                    sa[kt][qt][g] = p;
                    sm += p;
                }
            }
            sm += __shfl_xor(sm, 16);
            sm += __shfl_xor(sm, 32);
            rinv[qt] = 1.0f / sm;   // normalization deferred to O
        }

        // P fragments in-register
        short8 ap[2][2];
        #pragma unroll
        for (int qt = 0; qt < 2; ++qt) {
            #pragma unroll
            for (int kk = 0; kk < 2; ++kk)
                ap[qt][kk] = qshuf(sa[2 * kk][qt], sa[2 * kk + 1][qt], lane);
        }

        short8 bv[2][2];
        #pragma unroll
        for (int nv = 0; nv < 2; ++nv)
            #pragma unroll
            for (int kk = 0; kk < 2; ++kk)
                bv[nv][kk] = *reinterpret_cast<const short8*>(
                    vsT + (h * HD + nv * 16 + r) * VTS + kk * 32 + q * 8);

        // O^T = mfma(V^T, P^T): lane col=query (r) -> rinv lane-local; -> osm
        #pragma unroll
        for (int qt = 0; qt < 2; ++qt) {
            #pragma unroll
            for (int nv = 0; nv < 2; ++nv) {
                floatx4 o = (floatx4){0.f, 0.f, 0.f, 0.f};
                o = __builtin_amdgcn_mfma_f32_16x16x32_bf16(bv[nv][0], ap[qt][0], o, 0, 0, 0);
                o = __builtin_amdgcn_mfma_f32_16x16x32_bf16(bv[nv][1], ap[qt][1], o, 0, 0, 0);
                uint2v uo;
                uo.x = pkbf(o[0] * rinv[qt], o[1] * rinv[qt]);
                uo.y = pkbf(o[2] * rinv[qt], o[3] * rinv[qt]);
                *reinterpret_cast<uint2v*>(
                    osm + (half * 32 + qt * 16 + r) * RS + h * HD + nv * 16 + q * 4) = uo;
            }
        }
    }
    __syncthreads();   // osm complete

    // ---------------- Phase 3: out = O * Wproj^T + b ----------------
    short8 ao[4][6];
    #pragma unroll
    for (int mt = 0; mt < 4; ++mt) {
        #pragma unroll
        for (int s = 0; s < 6; ++s)
            ao[mt][s] = *reinterpret_cast<const short8*>(osm + (mt * 16 + r) * RS + s * 32 + q * 8);
    }

    float* ob = out + (size_t)bw * (NTOK * DIM);
    #pragma unroll 1
    for (int nt = 0; nt < 3; ++nt) {
        const int d0 = wave * 48 + nt * 16;
        const float4 b4 = *reinterpret_cast<const float4*>(bproj + d0 + q * 4);
        floatx4 acc[4];
        #pragma unroll
        for (int mt = 0; mt < 4; ++mt) acc[mt] = (floatx4){b4.x, b4.y, b4.z, b4.w};
        #pragma unroll
        for (int s = 0; s < 6; ++s) {
            const short8 w8 = ldp((d0 + r) * DIM + s * 32 + q * 8);
            #pragma unroll
            for (int mt = 0; mt < 4; ++mt)      // swapped: D col=token, row=outdim
                acc[mt] = __builtin_amdgcn_mfma_f32_16x16x32_bf16(w8, ao[mt][s], acc[mt], 0, 0, 0);
        }
        #pragma unroll
        for (int mt = 0; mt < 4; ++mt) {        // 4 consecutive dims -> float4 store
            float4 st;
            st.x = acc[mt][0]; st.y = acc[mt][1]; st.z = acc[mt][2]; st.w = acc[mt][3];
            *reinterpret_cast<float4*>(ob + (mt * 16 + r) * DIM + d0 + q * 4) = st;
        }
    }
}

extern "C" void kernel_launch(void* const* d_in, const int* in_sizes, int n_in,
                              void* d_out, int out_size, void* d_ws, size_t ws_size,
                              hipStream_t stream) {
    const float* x    = (const float*)d_in[0];
    const float* mask = (const float*)d_in[1];
    const float* wqkv = (const float*)d_in[2];
    const float* wp   = (const float*)d_in[3];
    const float* bp   = (const float*)d_in[4];
    float* out = (float*)d_out;
    const int nwin = in_sizes[0] / (NTOK * DIM);   // 4096 windows
    const size_t needw = (size_t)(WQN + WPN) * sizeof(short);
    if (d_ws != nullptr && ws_size >= needw) {
        short* wqb = (short*)d_ws;
        short* wpb = wqb + WQN;
        wprep<<<192, 256, 0, stream>>>(wqkv, wp, wqb, wpb);
        wattn_fused<1><<<nwin, 256, 0, stream>>>(x, mask, wqkv, wp, bp, out, wqb, wpb);
    } else {
        wattn_fused<0><<<nwin, 256, 0, stream>>>(x, mask, wqkv, wp, bp, out, nullptr, nullptr);
    }
}